// Round 6
// baseline (17.208 us; speedup 1.0000x reference)
//
#include <hip/hip_runtime.h>

// YIN pitch, B=8, n=80000, fp32. SR=8000 HOP=80 TAU_MIN=20 TAU_MAX=133 W=133
// FRAME_LEN=266 THRESH=0.2 ; n_frames=997, output 996/batch.
//
// v6: ONE FRAME PER WAVE (7968 waves, 7.8/SIMD) with 4 tau/lane preserved.
// The wave's two 32-lane halves split the j-range of the SAME frame:
//   half 0: j = 0..67   (17 chunks)
//   half 1: j = 68..131 (16 chunks) + j=132 (partial chunk)
// Each half: lane l2 owns tau = 4*l2+1..4*l2+4; stream = b128 reads at
// f + 68*h + 4*l2; broadcast = b128 at per-half-uniform address.
// Partial d combined via __shfl_xor(.,32). Tail taus 129..133 j-split over
// all 64 lanes + scan64 (totals land on lane 63). CMNDF scan32 + ballot-free
// min-pick per half (v5 epilogue); output written by lane 63.

#define NF_OUT 996
#define NSAMP  80000
#define FPB    4
#define BPB    (NF_OUT / FPB)   // 249
#define CHUNKD 512              // 266 + 3*80 = 506, padded
#define TH     0.2f
#define EPS    1e-8f

template<int CTRL, int RMASK>
__device__ __forceinline__ float dpp_add(float x) {
    int t = __builtin_amdgcn_update_dpp(0, __builtin_bit_cast(int, x), CTRL, RMASK, 0xF, false);
    return x + __builtin_bit_cast(float, t);
}
template<int CTRL, int RMASK>
__device__ __forceinline__ int dpp_min(int x) {
    int t = __builtin_amdgcn_update_dpp(0x7FFFFFFF, x, CTRL, RMASK, 0xF, false);
    return (t < x) ? t : x;
}
// inclusive scan within each 32-lane half (total at l2=31 of each half)
__device__ __forceinline__ float scan32_add(float v) {
    v = dpp_add<0x111, 0xF>(v);   // row_shr:1
    v = dpp_add<0x112, 0xF>(v);   // row_shr:2
    v = dpp_add<0x114, 0xF>(v);   // row_shr:4
    v = dpp_add<0x118, 0xF>(v);   // row_shr:8
    v = dpp_add<0x142, 0xA>(v);   // row_bcast:15 -> rows 1,3
    return v;
}
// inclusive scan over all 64 lanes (total at lane 63)
__device__ __forceinline__ float scan64_add(float v) {
    v = dpp_add<0x111, 0xF>(v);
    v = dpp_add<0x112, 0xF>(v);
    v = dpp_add<0x114, 0xF>(v);
    v = dpp_add<0x118, 0xF>(v);
    v = dpp_add<0x142, 0xA>(v);
    v = dpp_add<0x143, 0xC>(v);   // row_bcast:31 -> rows 2,3
    return v;
}
// min within each 32-lane half (result at l2=31 of each half)
__device__ __forceinline__ int red32_min(int v) {
    v = dpp_min<0x111, 0xF>(v);
    v = dpp_min<0x112, 0xF>(v);
    v = dpp_min<0x114, 0xF>(v);
    v = dpp_min<0x118, 0xF>(v);
    v = dpp_min<0x142, 0xA>(v);
    return v;
}

#define MAC4(CURV, NXTV, FRV) do {                                             \
    float w0=CURV.y,w1=CURV.z,w2=CURV.w,w3=NXTV.x,w4=NXTV.y,w5=NXTV.z,w6=NXTV.w; \
    float d_;                                                                  \
    d_=FRV.x-w0; a0=fmaf(d_,d_,a0); d_=FRV.y-w1; a0=fmaf(d_,d_,a0);            \
    d_=FRV.z-w2; a0=fmaf(d_,d_,a0); d_=FRV.w-w3; a0=fmaf(d_,d_,a0);            \
    d_=FRV.x-w1; a1=fmaf(d_,d_,a1); d_=FRV.y-w2; a1=fmaf(d_,d_,a1);            \
    d_=FRV.z-w3; a1=fmaf(d_,d_,a1); d_=FRV.w-w4; a1=fmaf(d_,d_,a1);            \
    d_=FRV.x-w2; a2=fmaf(d_,d_,a2); d_=FRV.y-w3; a2=fmaf(d_,d_,a2);            \
    d_=FRV.z-w4; a2=fmaf(d_,d_,a2); d_=FRV.w-w5; a2=fmaf(d_,d_,a2);            \
    d_=FRV.x-w3; a3=fmaf(d_,d_,a3); d_=FRV.y-w4; a3=fmaf(d_,d_,a3);            \
    d_=FRV.z-w5; a3=fmaf(d_,d_,a3); d_=FRV.w-w6; a3=fmaf(d_,d_,a3);            \
} while (0)

__global__ __launch_bounds__(256, 6) void yin_kernel(const float* __restrict__ x,
                                                     float* __restrict__ out) {
    const int bx = blockIdx.x;
    const int b  = bx / BPB;
    const int fb = bx - b * BPB;
    const float* __restrict__ xrow = x + (size_t)b * NSAMP + (size_t)fb * (FPB * 80);

    __shared__ __align__(16) float sch[CHUNKD];
    const int t = threadIdx.x;
    if (t < 128)
        *(float4*)(sch + 4 * t) = *(const float4*)(xrow + 4 * t);
    __syncthreads();

    const int lane = t & 63;
    const int w    = t >> 6;        // wave id = frame within block (0..3)
    const int h    = lane >> 5;     // half: j-range select
    const int l2   = lane & 31;
    const float* f   = sch + w * 80;        // this wave's frame
    const float* bcp = f + 68 * h;          // per-half broadcast base (16B aligned)
    const float* qF  = bcp + 4 * l2;        // per-lane stream base (16B aligned)

    // ---- difference fn partials: tau = 4*l2+1..4*l2+4, j in this half's range ----
    float4 cur = *(const float4*)(qF);
    float a0 = 0.f, a1 = 0.f, a2 = 0.f, a3 = 0.f;

    #pragma unroll 2
    for (int c = 0; c < 16; ++c) {          // j = J0 + 4c .. +3
        float4 nxt = *(const float4*)(qF + 4 * c + 4);
        float4 fr  = *(const float4*)(bcp + 4 * c);
        MAC4(cur, nxt, fr);
        cur = nxt;
    }
    {   // 17th block: half0 -> full chunk (j=64..67); half1 -> j=132 only
        float4 nxt = *(const float4*)(qF + 68);
        float4 fr  = *(const float4*)(bcp + 64);
        if (h == 0) {
            MAC4(cur, nxt, fr);
        } else {
            float d_;
            d_ = fr.x - cur.y; a0 = fmaf(d_, d_, a0);
            d_ = fr.x - cur.z; a1 = fmaf(d_, d_, a1);
            d_ = fr.x - cur.w; a2 = fmaf(d_, d_, a2);
            d_ = fr.x - nxt.x; a3 = fmaf(d_, d_, a3);
        }
    }

    // ---- combine halves: full d[tau] in both halves ----
    a0 += __shfl_xor(a0, 32);
    a1 += __shfl_xor(a1, 32);
    a2 += __shfl_xor(a2, 32);
    a3 += __shfl_xor(a3, 32);

    // ---- tail taus 129..133: j-split over all 64 lanes ----
    float p[5] = {0.f, 0.f, 0.f, 0.f, 0.f};
    {
        float fj1 = f[lane];
        float fj2 = f[lane + 64];
        #pragma unroll
        for (int k = 0; k < 5; ++k) {
            float d1 = fj1 - f[lane + 129 + k]; p[k] = fmaf(d1, d1, p[k]);
            float d2 = fj2 - f[lane + 193 + k]; p[k] = fmaf(d2, d2, p[k]);
        }
        if (lane < 5) {
            float fj3 = f[128 + lane];
            #pragma unroll
            for (int k = 0; k < 5; ++k) {
                float d3 = fj3 - f[257 + lane + k]; p[k] = fmaf(d3, d3, p[k]);
            }
        }
    }
    #pragma unroll
    for (int k = 0; k < 5; ++k) p[k] = scan64_add(p[k]);   // totals at lane 63

    // ---- CMNDF cum prefix per half (identical data in both halves) ----
    float L = a0 + a1 + a2 + a3;
    float inc = scan32_add(L);
    float excl = inc - L;
    float c0 = excl + a0;
    float c1 = c0 + a1;
    float c2 = c1 + a2;
    float c3 = c2 + a3;

    // ---- candidate pick: d*tau < TH*max(cum,eps), tau >= 20 ----
    int best = 0x7FFFFFFF;
    const int tau0 = 4 * l2 + 1;
    if (tau0     >= 20 && a0 * (float)(tau0)     < TH * fmaxf(c0, EPS)) best = tau0;
    if (best == 0x7FFFFFFF && tau0 + 1 >= 20 && a1 * (float)(tau0 + 1) < TH * fmaxf(c1, EPS)) best = tau0 + 1;
    if (best == 0x7FFFFFFF && tau0 + 2 >= 20 && a2 * (float)(tau0 + 2) < TH * fmaxf(c2, EPS)) best = tau0 + 2;
    if (best == 0x7FFFFFFF && tau0 + 3 >= 20 && a3 * (float)(tau0 + 3) < TH * fmaxf(c3, EPS)) best = tau0 + 3;

    if (lane == 63) {   // lane 63 holds cum[128] (c3) and the scanned p totals
        float cum = c3;
        #pragma unroll
        for (int k = 0; k < 5; ++k) {
            cum += p[k];
            if (p[k] * (float)(129 + k) < TH * fmaxf(cum, EPS))
                best = (best < 129 + k) ? best : (129 + k);
        }
    }
    best = red32_min(best);     // per-half min -> l2=31 (lane 31 and lane 63)

    if (lane == 63) {
        int fr_idx = fb * FPB + w;
        out[(size_t)b * NF_OUT + fr_idx] =
            (best == 0x7FFFFFFF) ? 0.0f : 8000.0f / (float)best;
    }
}

extern "C" void kernel_launch(void* const* d_in, const int* in_sizes, int n_in,
                              void* d_out, int out_size, void* d_ws, size_t ws_size,
                              hipStream_t stream) {
    (void)in_sizes; (void)n_in; (void)d_ws; (void)ws_size; (void)out_size;
    const float* x = (const float*)d_in[0];
    float* out = (float*)d_out;
    yin_kernel<<<dim3(8 * BPB), dim3(256), 0, stream>>>(x, out);
}

// Round 7
// 16.406 us; speedup vs baseline: 1.0489x; 1.0489x over previous
//
#include <hip/hip_runtime.h>

// YIN pitch, B=8, n=80000, fp32. SR=8000 HOP=80 TAU_MIN=20 TAU_MAX=133 W=133
// FRAME_LEN=266 THRESH=0.2 ; n_frames=997, output 996/batch.
//
// v7: 64-thr (1-wave) blocks, 4 frames/wave (one per 16-lane quarter),
// 8 tau/lane: lane l4 owns tau = 8*l4+1 .. 8*l4+8 (tau 1..128; tail 129..133
// j-split). Per 4-j chunk: 1 stream ds_read_b128 + 1 quarter-uniform bcast
// b128 feed 32 fma (fma:DS = 16:1, one DS instr serves 4 frames). Stream
// prefetched 3 chunks ahead (reg rotation R0..R3). All cross-lane via
// 16-lane row-confined DPP (row_shr scans need no bcast step). No divides.

#define NF_OUT 996
#define NSAMP  80000
#define BPB    249           // 996/4 frames per block
#define TH     0.2f
#define EPS    1e-8f
#define INF_I  0x7FFFFFFF

template<int CTRL>
__device__ __forceinline__ float dpp_add16(float x) {
    int t = __builtin_amdgcn_update_dpp(0, __builtin_bit_cast(int, x), CTRL, 0xF, 0xF, false);
    return x + __builtin_bit_cast(float, t);
}
template<int CTRL>
__device__ __forceinline__ int dpp_min16(int x) {
    int t = __builtin_amdgcn_update_dpp(INF_I, x, CTRL, 0xF, 0xF, false);
    return t < x ? t : x;
}
// inclusive sum-scan within each 16-lane row (total lands at l4=15)
__device__ __forceinline__ float scan16_add(float v) {
    v = dpp_add16<0x111>(v);   // row_shr:1
    v = dpp_add16<0x112>(v);   // row_shr:2
    v = dpp_add16<0x114>(v);   // row_shr:4
    v = dpp_add16<0x118>(v);   // row_shr:8
    return v;
}
// min within each 16-lane row (result at l4=15)
__device__ __forceinline__ int red16_min(int v) {
    v = dpp_min16<0x111>(v);
    v = dpp_min16<0x112>(v);
    v = dpp_min16<0x114>(v);
    v = dpp_min16<0x118>(v);
    return v;
}

// 32 fma: q=0..3 (j=4c+q), k=1..8 (tau=8*l4+k); window W[m]=f[8*l4+4c+m], m=0..11
#define MAC8(FR, W0, W1, W2) do { float d_;                                    \
    d_=FR.x-W0.y; a1=fmaf(d_,d_,a1); d_=FR.x-W0.z; a2=fmaf(d_,d_,a2);          \
    d_=FR.x-W0.w; a3=fmaf(d_,d_,a3); d_=FR.x-W1.x; a4=fmaf(d_,d_,a4);          \
    d_=FR.x-W1.y; a5=fmaf(d_,d_,a5); d_=FR.x-W1.z; a6=fmaf(d_,d_,a6);          \
    d_=FR.x-W1.w; a7=fmaf(d_,d_,a7); d_=FR.x-W2.x; a8=fmaf(d_,d_,a8);          \
    d_=FR.y-W0.z; a1=fmaf(d_,d_,a1); d_=FR.y-W0.w; a2=fmaf(d_,d_,a2);          \
    d_=FR.y-W1.x; a3=fmaf(d_,d_,a3); d_=FR.y-W1.y; a4=fmaf(d_,d_,a4);          \
    d_=FR.y-W1.z; a5=fmaf(d_,d_,a5); d_=FR.y-W1.w; a6=fmaf(d_,d_,a6);          \
    d_=FR.y-W2.x; a7=fmaf(d_,d_,a7); d_=FR.y-W2.y; a8=fmaf(d_,d_,a8);          \
    d_=FR.z-W0.w; a1=fmaf(d_,d_,a1); d_=FR.z-W1.x; a2=fmaf(d_,d_,a2);          \
    d_=FR.z-W1.y; a3=fmaf(d_,d_,a3); d_=FR.z-W1.z; a4=fmaf(d_,d_,a4);          \
    d_=FR.z-W1.w; a5=fmaf(d_,d_,a5); d_=FR.z-W2.x; a6=fmaf(d_,d_,a6);          \
    d_=FR.z-W2.y; a7=fmaf(d_,d_,a7); d_=FR.z-W2.z; a8=fmaf(d_,d_,a8);          \
    d_=FR.w-W1.x; a1=fmaf(d_,d_,a1); d_=FR.w-W1.y; a2=fmaf(d_,d_,a2);          \
    d_=FR.w-W1.z; a3=fmaf(d_,d_,a3); d_=FR.w-W1.w; a4=fmaf(d_,d_,a4);          \
    d_=FR.w-W2.x; a5=fmaf(d_,d_,a5); d_=FR.w-W2.y; a6=fmaf(d_,d_,a6);          \
    d_=FR.w-W2.z; a7=fmaf(d_,d_,a7); d_=FR.w-W2.w; a8=fmaf(d_,d_,a8);          \
} while (0)

__global__ __launch_bounds__(64) void yin_kernel(const float* __restrict__ x,
                                                 float* __restrict__ out) {
    const int bx = blockIdx.x;
    const int b  = bx / BPB;
    const int fb = bx - b * BPB;
    const float* __restrict__ xrow = x + (size_t)b * NSAMP + (size_t)fb * 320;

    __shared__ __align__(16) float sch[512];
    const int t = threadIdx.x;          // 0..63
    // coalesced staging: 512 floats (safe: fb<=248 -> max idx 79872 < 80000)
    *(float4*)(sch + 4 * t)       = *(const float4*)(xrow + 4 * t);
    *(float4*)(sch + 4 * t + 256) = *(const float4*)(xrow + 4 * t + 256);
    __syncthreads();

    const int q  = t >> 4;              // quarter = frame select (0..3)
    const int l4 = t & 15;
    const float* f  = sch + 80 * q;     // frame base (16B aligned)
    const float* gp = f + 8 * l4;       // stream base (16B aligned)

    // ---- difference fn, tau = 8*l4+1 .. 8*l4+8 ----
    float4 R0 = *(const float4*)(gp);
    float4 R1 = *(const float4*)(gp + 4);
    float4 R2 = *(const float4*)(gp + 8);
    float4 R3;
    const float4 S0 = R0, S1 = R1;      // f[8*l4 .. 8*l4+7] for tail j-split
    float a1=0.f,a2=0.f,a3=0.f,a4=0.f,a5=0.f,a6=0.f,a7=0.f,a8=0.f;

    for (int c = 0; c < 32; c += 4) {   // chunks 0..31 (j = 0..127)
        float4 FR;
        R3 = *(const float4*)(gp + 4*c + 12); FR = *(const float4*)(f + 4*c);      MAC8(FR, R0, R1, R2);
        R0 = *(const float4*)(gp + 4*c + 16); FR = *(const float4*)(f + 4*c + 4);  MAC8(FR, R1, R2, R3);
        R1 = *(const float4*)(gp + 4*c + 20); FR = *(const float4*)(f + 4*c + 8);  MAC8(FR, R2, R3, R0);
        R2 = *(const float4*)(gp + 4*c + 24); FR = *(const float4*)(f + 4*c + 12); MAC8(FR, R3, R0, R1);
    }
    // after loop: R0 = f[8l4+128..131], R1 = f[8l4+132..135], R2 = f[8l4+136..139]
    const float4 R35 = *(const float4*)(gp + 140);      // f[8l4+140..143]
    {   // chunk 32: j = 128..131
        float4 FR = *(const float4*)(f + 128);
        MAC8(FR, R0, R1, R2);
    }
    {   // j = 132: a_k += (f[132] - f[8l4+132+k])^2
        float frx = f[132];
        float d_;
        d_=frx-R1.y; a1=fmaf(d_,d_,a1); d_=frx-R1.z; a2=fmaf(d_,d_,a2);
        d_=frx-R1.w; a3=fmaf(d_,d_,a3); d_=frx-R2.x; a4=fmaf(d_,d_,a4);
        d_=frx-R2.y; a5=fmaf(d_,d_,a5); d_=frx-R2.z; a6=fmaf(d_,d_,a6);
        d_=frx-R2.w; a7=fmaf(d_,d_,a7); d_=frx-R35.x; a8=fmaf(d_,d_,a8);
    }

    // ---- tail taus 129..133: d[129+k] = sum_j (f[j]-f[j+129+k])^2, j-split ----
    // lane covers j = 8*l4+r (r=0..7, j<=127); values all in registers.
    float SA[8]  = {S0.x,S0.y,S0.z,S0.w,S1.x,S1.y,S1.z,S1.w};
    float WA[13] = {R0.x,R0.y,R0.z,R0.w,R1.x,R1.y,R1.z,R1.w,
                    R2.x,R2.y,R2.z,R2.w,R35.x};   // WA[m] = f[8l4+128+m]
    float p[5] = {0.f,0.f,0.f,0.f,0.f};
    #pragma unroll
    for (int k = 0; k < 5; ++k) {
        #pragma unroll
        for (int r = 0; r < 8; ++r) {
            float d_ = SA[r] - WA[1 + k + r];     // f[j] - f[j+129+k]
            p[k] = fmaf(d_, d_, p[k]);
        }
    }
    if (l4 < 5) {   // leftover j = 128..132, one per lane
        float fA = f[128 + l4];
        #pragma unroll
        for (int k = 0; k < 5; ++k) {
            float d_ = fA - f[257 + l4 + k];
            p[k] = fmaf(d_, d_, p[k]);
        }
    }
    #pragma unroll
    for (int k = 0; k < 5; ++k) p[k] = scan16_add(p[k]);   // totals at l4=15

    // ---- CMNDF cum prefix: within-lane serial + 16-lane DPP scan ----
    float s1=a1, s2=s1+a2, s3=s2+a3, s4=s3+a4, s5=s4+a5, s6=s5+a6, s7=s6+a7, s8=s7+a8;
    float incl = scan16_add(s8);
    float excl = incl - s8;
    float c1=excl+s1, c2=excl+s2, c3=excl+s3, c4=excl+s4,
          c5=excl+s5, c6=excl+s6, c7=excl+s7, c8=excl+s8;

    // ---- pick: first tau with d*tau < TH*max(cum,eps), tau >= 20 ----
    int best = INF_I;
    const int tb = 8 * l4;
    if (tb+1 >= 20 && a1*(float)(tb+1) < TH*fmaxf(c1,EPS)) best = tb+1;
    if (best==INF_I && tb+2 >= 20 && a2*(float)(tb+2) < TH*fmaxf(c2,EPS)) best = tb+2;
    if (best==INF_I && tb+3 >= 20 && a3*(float)(tb+3) < TH*fmaxf(c3,EPS)) best = tb+3;
    if (best==INF_I && tb+4 >= 20 && a4*(float)(tb+4) < TH*fmaxf(c4,EPS)) best = tb+4;
    if (best==INF_I && tb+5 >= 20 && a5*(float)(tb+5) < TH*fmaxf(c5,EPS)) best = tb+5;
    if (best==INF_I && tb+6 >= 20 && a6*(float)(tb+6) < TH*fmaxf(c6,EPS)) best = tb+6;
    if (best==INF_I && tb+7 >= 20 && a7*(float)(tb+7) < TH*fmaxf(c7,EPS)) best = tb+7;
    if (best==INF_I && tb+8 >= 20 && a8*(float)(tb+8) < TH*fmaxf(c8,EPS)) best = tb+8;
    best = red16_min(best);             // min tau of quarter at l4=15

    if (l4 == 15) {                     // holds cum[128]=c8 and scanned p[k]
        float cum = c8;
        #pragma unroll
        for (int k = 0; k < 5; ++k) {
            cum += p[k];
            if (p[k] * (float)(129 + k) < TH * fmaxf(cum, EPS))
                best = (best < 129 + k) ? best : (129 + k);
        }
        out[(size_t)b * NF_OUT + fb * 4 + q] =
            (best == INF_I) ? 0.0f : 8000.0f / (float)best;
    }
}

extern "C" void kernel_launch(void* const* d_in, const int* in_sizes, int n_in,
                              void* d_out, int out_size, void* d_ws, size_t ws_size,
                              hipStream_t stream) {
    (void)in_sizes; (void)n_in; (void)d_ws; (void)ws_size; (void)out_size;
    const float* x = (const float*)d_in[0];
    float* out = (float*)d_out;
    yin_kernel<<<dim3(8 * BPB), dim3(64), 0, stream>>>(x, out);
}